// Round 7
// baseline (185.185 us; speedup 1.0000x reference)
//
#include <hip/hip_runtime.h>
#include <math.h>
#include <stdint.h>

#define BATCH 64
#define SEQ   101
#define HID   512
#define NKQ   100      // N*K
#define KCLS  10
#define INV_TEMP 0.04419417382415922f   // 1/sqrt(512)

typedef short bf16x8 __attribute__((ext_vector_type(8)));
typedef float f32x4  __attribute__((ext_vector_type(4)));

// ws plane sizes (in shorts)
#define QK_PLANE ((size_t)BATCH * SEQ * HID)    // 3,309,568
#define VT_PLANE ((size_t)BATCH * HID * 128)    // 4,194,304

// truncation split: x == hi + lo to ~2^-17 rel
__device__ inline void split_bf16(float x, short& hi, short& lo) {
    uint32_t u = __builtin_bit_cast(uint32_t, x);
    hi = (short)(u >> 16);
    float hf = __builtin_bit_cast(float, u & 0xFFFF0000u);
    float l  = x - hf;
    lo = (short)(__builtin_bit_cast(uint32_t, l) >> 16);
}

// ---------------- Prep: one-shot fp32 -> bf16 hi/lo planes ------------------
// blocks [0,256): v transpose to [b][h][j(128 pad)] hi/lo.
// blocks [256,768): q,k row-order conversion (grid-stride).
__global__ __launch_bounds__(256)
void prep_bf16(const float* __restrict__ q, const float* __restrict__ k,
               const float* __restrict__ v,
               short* __restrict__ qh, short* __restrict__ ql,
               short* __restrict__ kh, short* __restrict__ kl,
               short* __restrict__ vh, short* __restrict__ vl) {
    const int tid = threadIdx.x;
    if (blockIdx.x < 256) {
        __shared__ float tile[SEQ][132];
        const int b = blockIdx.x & 63, hc = (blockIdx.x >> 6) * 128;
        const float* vb = v + (size_t)b * SEQ * HID + hc;
        for (int f = tid; f < SEQ * 32; f += 256) {
            int r = f >> 5, c = (f & 31) << 2;
            *(float4*)&tile[r][c] = *(const float4*)(vb + (size_t)r * HID + c);
        }
        __syncthreads();
        const int hl = tid >> 1;              // 0..127
        const int j0 = (tid & 1) * 64;
        const size_t ro = ((size_t)b * HID + hc + hl) * 128 + j0;
        for (int jj = 0; jj < 64; jj += 4) {
            short4 hv, lv;
            int j = j0 + jj;
            split_bf16(j + 0 < SEQ ? tile[j + 0][hl] : 0.f, hv.x, lv.x);
            split_bf16(j + 1 < SEQ ? tile[j + 1][hl] : 0.f, hv.y, lv.y);
            split_bf16(j + 2 < SEQ ? tile[j + 2][hl] : 0.f, hv.z, lv.z);
            split_bf16(j + 3 < SEQ ? tile[j + 3][hl] : 0.f, hv.w, lv.w);
            *(short4*)(vh + ro + jj) = hv;
            *(short4*)(vl + ro + jj) = lv;
        }
    } else {
        const size_t per = QK_PLANE / 4;      // float4 count per tensor
        for (size_t f = (size_t)(blockIdx.x - 256) * 256 + tid;
             f < 2 * per; f += (size_t)512 * 256) {
            size_t e = f;
            const float* src; short *dh, *dl;
            if (e < per) { src = q; dh = qh; dl = ql; }
            else         { e -= per; src = k; dh = kh; dl = kl; }
            float4 x = ((const float4*)src)[e];
            short4 hv, lv;
            split_bf16(x.x, hv.x, lv.x);
            split_bf16(x.y, hv.y, lv.y);
            split_bf16(x.z, hv.z, lv.z);
            split_bf16(x.w, hv.w, lv.w);
            *(short4*)(dh + e * 4) = hv;
            *(short4*)(dl + e * 4) = lv;
        }
    }
}

// ---------------- Fused: QK^T -> softmax -> PV + epilogue -------------------
// Flat grid 896 = 64 b x 7 i-tiles x 2 h-groups; b = id&63 keeps all blocks of
// a batch on one XCD (L2 reuse of its bf16 planes). 512 thr = 8 waves.
// P1: wave w -> j-strip [16w,16w+16). P3: wave w -> 32-h strip of hg's 256 h.
__global__ __launch_bounds__(512, 4)
void fused_attn(const float* __restrict__ v, const float* __restrict__ aw,
                const short* __restrict__ qh, const short* __restrict__ ql,
                const short* __restrict__ kh, const short* __restrict__ kl,
                const short* __restrict__ vh, const short* __restrict__ vl,
                float* __restrict__ out, float* __restrict__ attn) {
    __shared__ float sc[16][132];        // fp32 scores -> normalized attn
    __shared__ short ah_s[16][136];      // attn hi (A-operand layout)
    __shared__ short al_s[16][136];      // attn lo
    __shared__ short mh_s[16][136];      // class-masked attn hi

    const int id  = blockIdx.x;
    const int b   = id & 63;
    const int rr  = id >> 6;             // 0..13
    const int it  = rr % 7, hg = rr / 7;
    const int i0  = it * 16;
    const int tid = threadIdx.x;
    const int wv  = tid >> 6, lane = tid & 63;
    const int m   = lane & 15;           // A-row / B-col / C-col index
    const int kq  = (lane >> 4) * 8;     // k-offset within 32-step
    const int rq  = (lane >> 4) * 4;     // C-row quad base

    const float* vb = v + (size_t)b * SEQ * HID;

    // ---------------- Phase 1: QK^T (pure load->MFMA) ----------------
    {
        const int j0w = wv * 16;
        int qrow = i0 + m;  if (qrow > NKQ) qrow = NKQ;
        int krow = j0w + m; if (krow > NKQ) krow = NKQ;
        const short* qhr = qh + ((size_t)b * SEQ + qrow) * HID + kq;
        const short* qlr = ql + ((size_t)b * SEQ + qrow) * HID + kq;
        const short* khr = kh + ((size_t)b * SEQ + krow) * HID + kq;
        const short* klr = kl + ((size_t)b * SEQ + krow) * HID + kq;
        f32x4 acc = {};
        #pragma unroll 4
        for (int ks = 0; ks < HID; ks += 32) {
            bf16x8 aH = *(const bf16x8*)(qhr + ks);
            bf16x8 aL = *(const bf16x8*)(qlr + ks);
            bf16x8 bH = *(const bf16x8*)(khr + ks);
            bf16x8 bL = *(const bf16x8*)(klr + ks);
            acc = __builtin_amdgcn_mfma_f32_16x16x32_bf16(aH, bH, acc, 0, 0, 0);
            acc = __builtin_amdgcn_mfma_f32_16x16x32_bf16(aH, bL, acc, 0, 0, 0);
            acc = __builtin_amdgcn_mfma_f32_16x16x32_bf16(aL, bH, acc, 0, 0, 0);
        }
        #pragma unroll
        for (int r = 0; r < 4; ++r)
            sc[rq + r][j0w + m] = acc[r];
    }
    __syncthreads();

    // ---------------- Phase 2: softmax + bf16 conversion ----------------
    {
        const int row = tid >> 5, t32 = tid & 31;
        const int gi  = i0 + row;
        float mx = -1e30f;
        for (int j = t32; j < SEQ; j += 32) {
            float s = sc[row][j] * INV_TEMP;
            sc[row][j] = s;
            mx = fmaxf(mx, s);
        }
        #pragma unroll
        for (int off = 1; off < 32; off <<= 1) mx = fmaxf(mx, __shfl_xor(mx, off));
        float sum = 0.f;
        for (int j = t32; j < SEQ; j += 32) {
            float e = __expf(sc[row][j] - mx);
            sc[row][j] = e;
            sum += e;
        }
        #pragma unroll
        for (int off = 1; off < 32; off <<= 1) sum += __shfl_xor(sum, off);
        const float inv = 1.f / sum;
        const int ci = gi / KCLS;
        float* arow = attn + ((size_t)b * SEQ + gi) * SEQ;
        for (int j = t32; j < SEQ; j += 32) {
            float a = sc[row][j] * inv;
            sc[row][j] = a;
            if (hg == 0 && gi < SEQ) arow[j] = a;
            short h, l; split_bf16(a, h, l);
            ah_s[row][j] = h; al_s[row][j] = l;
            mh_s[row][j] = ((j / KCLS) == ci) ? h : (short)0;
        }
        for (int j = SEQ + t32; j < 136; j += 32) {   // zero pad
            ah_s[row][j] = 0; al_s[row][j] = 0; mh_s[row][j] = 0;
        }
    }
    __syncthreads();

    // ------- Phase 3: T = attn@v (hi/lo), U = amask@v (single) -------
    const int hb = hg * 256 + wv * 32;
    f32x4 T[2] = {}, U[2] = {};
    #pragma unroll
    for (int ks = 0; ks < 128; ks += 32) {
        const bf16x8 Ah = *(const bf16x8*)&ah_s[m][ks + kq];
        const bf16x8 Al = *(const bf16x8*)&al_s[m][ks + kq];
        const bf16x8 Mh = *(const bf16x8*)&mh_s[m][ks + kq];
        #pragma unroll
        for (int ht = 0; ht < 2; ++ht) {
            const int h = hb + ht * 16 + m;
            const size_t vo = ((size_t)b * HID + h) * 128 + ks + kq;
            const bf16x8 Bh = *(const bf16x8*)(vh + vo);
            const bf16x8 Bl = *(const bf16x8*)(vl + vo);
            T[ht] = __builtin_amdgcn_mfma_f32_16x16x32_bf16(Ah, Bh, T[ht], 0, 0, 0);
            T[ht] = __builtin_amdgcn_mfma_f32_16x16x32_bf16(Ah, Bl, T[ht], 0, 0, 0);
            T[ht] = __builtin_amdgcn_mfma_f32_16x16x32_bf16(Al, Bh, T[ht], 0, 0, 0);
            U[ht] = __builtin_amdgcn_mfma_f32_16x16x32_bf16(Mh, Bh, U[ht], 0, 0, 0);
        }
    }

    // ---------------- Phase 4: fused region-decomposed epilogue -------------
    #pragma unroll
    for (int ht = 0; ht < 2; ++ht) {
        const int h = hb + ht * 16 + m;
        const float w0 = aw[0 * HID + h], w1 = aw[1 * HID + h], w2 = aw[2 * HID + h];
        const float w3 = aw[3 * HID + h], w4 = aw[4 * HID + h], w5 = aw[5 * HID + h];
        const float vN = vb[(size_t)NKQ * HID + h];
        #pragma unroll
        for (int r = 0; r < 4; ++r) {
            const int il = rq + r;
            const int i  = i0 + il;
            if (i >= SEQ) continue;
            const float t = T[ht][r], u = U[ht][r];
            const float aiN = sc[il][NKQ];
            float o;
            if (i < NKQ) {
                const float aii = sc[il][i];
                const float vi  = vb[(size_t)i * HID + h];
                o = w2 * t + (w1 - w2) * u + (w0 - w1) * aii * vi + (w3 - w2) * aiN * vN;
            } else {
                o = w4 * t + (w5 - w4) * aiN * vN;
            }
            out[((size_t)b * SEQ + i) * HID + h] = o;
        }
    }
}

extern "C" void kernel_launch(void* const* d_in, const int* in_sizes, int n_in,
                              void* d_out, int out_size, void* d_ws, size_t ws_size,
                              hipStream_t stream) {
    const float* q  = (const float*)d_in[0];
    const float* k  = (const float*)d_in[1];
    const float* v  = (const float*)d_in[2];
    const float* aw = (const float*)d_in[3];
    float* out  = (float*)d_out;
    float* attn = out + (size_t)BATCH * SEQ * HID;   // tuple output: [out | attn]

    short* qh = (short*)d_ws;
    short* ql = qh + QK_PLANE;
    short* kh = ql + QK_PLANE;
    short* kl = kh + QK_PLANE;
    short* vh = kl + QK_PLANE;
    short* vl = vh + VT_PLANE;

    prep_bf16<<<dim3(768), dim3(256), 0, stream>>>(q, k, v, qh, ql, kh, kl, vh, vl);
    fused_attn<<<dim3(896), dim3(512), 0, stream>>>(v, aw, qh, ql, kh, kl, vh, vl,
                                                    out, attn);
}

// Round 8
// 126.484 us; speedup vs baseline: 1.4641x; 1.4641x over previous
//
#include <hip/hip_runtime.h>
#include <math.h>
#include <stdint.h>

#define BATCH 64
#define SEQ   101
#define HID   512
#define NKQ   100      // N*K
#define KCLS  10
#define INV_TEMP 0.04419417382415922f   // 1/sqrt(512)

typedef short bf16x8 __attribute__((ext_vector_type(8)));
typedef float f32x4  __attribute__((ext_vector_type(4)));

// truncation split: x == hi + lo to ~2^-17 rel
__device__ inline void split_bf16(float x, short& hi, short& lo) {
    uint32_t u = __builtin_bit_cast(uint32_t, x);
    hi = (short)(u >> 16);
    float hf = __builtin_bit_cast(float, u & 0xFFFF0000u);
    float l  = x - hf;
    lo = (short)(__builtin_bit_cast(uint32_t, l) >> 16);
}

// ---------------- K1: QK^T (hi/lo bf16 MFMA) + softmax ----------------------
// grid 448 flat: b = id&63, i-tile = id>>6 (7 tiles of 16 rows). 512 thr.
// Wave w computes j-strip [16w, 16w+16). Writes attn (output) and apad
// (fp32, 128-col padded, 16B-aligned) for K2's aligned A-fragment loads.
__global__ __launch_bounds__(512, 4)
void qk_softmax(const float* __restrict__ q, const float* __restrict__ k,
                float* __restrict__ attn, float* __restrict__ apad) {
    __shared__ float sc[16][132];
    const int b   = blockIdx.x & 63;
    const int i0  = (blockIdx.x >> 6) * 16;
    const int tid = threadIdx.x;
    const int wv  = tid >> 6, lane = tid & 63;
    const int m   = lane & 15;
    const int kq  = (lane >> 4) * 8;
    const int rq  = (lane >> 4) * 4;

    const float* qb = q + (size_t)b * SEQ * HID;
    const float* kb = k + (size_t)b * SEQ * HID;

    // Phase 1: QK^T
    {
        const int j0w = wv * 16;
        int qrow = i0 + m;  if (qrow > NKQ) qrow = NKQ;   // clamp; C-rows >=101 unused
        int krow = j0w + m; if (krow > NKQ) krow = NKQ;   // clamp; C-cols >=101 unused
        const float* qr = qb + (size_t)qrow * HID + kq;
        const float* kr = kb + (size_t)krow * HID + kq;
        f32x4 acc = {};
        #pragma unroll 4
        for (int ks = 0; ks < HID; ks += 32) {
            float4 a0 = *(const float4*)(qr + ks);
            float4 a1 = *(const float4*)(qr + ks + 4);
            float4 b0 = *(const float4*)(kr + ks);
            float4 b1 = *(const float4*)(kr + ks + 4);
            float xa[8] = {a0.x,a0.y,a0.z,a0.w,a1.x,a1.y,a1.z,a1.w};
            float xb[8] = {b0.x,b0.y,b0.z,b0.w,b1.x,b1.y,b1.z,b1.w};
            bf16x8 aH, aL, bH, bL;
            #pragma unroll
            for (int e = 0; e < 8; ++e) { short h,l; split_bf16(xa[e],h,l); aH[e]=h; aL[e]=l; }
            #pragma unroll
            for (int e = 0; e < 8; ++e) { short h,l; split_bf16(xb[e],h,l); bH[e]=h; bL[e]=l; }
            acc = __builtin_amdgcn_mfma_f32_16x16x32_bf16(aH, bH, acc, 0, 0, 0);
            acc = __builtin_amdgcn_mfma_f32_16x16x32_bf16(aH, bL, acc, 0, 0, 0);
            acc = __builtin_amdgcn_mfma_f32_16x16x32_bf16(aL, bH, acc, 0, 0, 0);
        }
        #pragma unroll
        for (int r = 0; r < 4; ++r)
            sc[rq + r][j0w + m] = acc[r];
    }
    __syncthreads();

    // Phase 2: softmax (32 threads per row) + attn + apad writes
    {
        const int row = tid >> 5, t32 = tid & 31;
        const int gi  = i0 + row;
        float mx = -1e30f;
        for (int j = t32; j < SEQ; j += 32) {
            float s = sc[row][j] * INV_TEMP;
            sc[row][j] = s;
            mx = fmaxf(mx, s);
        }
        #pragma unroll
        for (int off = 1; off < 32; off <<= 1) mx = fmaxf(mx, __shfl_xor(mx, off));
        float sum = 0.f;
        for (int j = t32; j < SEQ; j += 32) {
            float e = __expf(sc[row][j] - mx);
            sc[row][j] = e;
            sum += e;
        }
        #pragma unroll
        for (int off = 1; off < 32; off <<= 1) sum += __shfl_xor(sum, off);
        const float inv = 1.f / sum;
        if (gi < SEQ) {
            float* arow = attn + ((size_t)b * SEQ + gi) * SEQ;
            float* prow = apad + ((size_t)b * SEQ + gi) * 128;
            for (int j = t32; j < SEQ; j += 32) {
                float a = sc[row][j] * inv;
                arow[j] = a;
                prow[j] = a;
            }
            for (int j = SEQ + t32; j < 128; j += 32) prow[j] = 0.f;
        }
    }
}

// ---------------- K2: T = attn@v (hi/lo), U = amask@v; epilogue -------------
// grid 1024 flat: b = id&63, h-strip = (id>>6)*32. 512 thr = 8 waves.
// Stage v[:,h0:h0+32] fp32 -> LDS; transpose+split to bf16 hi/lo once.
// Wave w (w<7) computes i-tile [16w,16w+16) x 32 h.
#define VR 36     // vraw row stride (floats), 144B: 16B-aligned
#define VT 144    // vt row stride (shorts), 288B: 16B-aligned

__global__ __launch_bounds__(512, 6)
void pv_out(const float* __restrict__ v, const float* __restrict__ aw,
            const float* __restrict__ apad, float* __restrict__ out) {
    __shared__ float vraw[SEQ][VR];    // 14.5 KB (fp32 v strip, exact vi/vN)
    __shared__ short vth[32][VT];      // 9.2 KB
    __shared__ short vtl[32][VT];      // 9.2 KB
    const int b   = blockIdx.x & 63;
    const int h0  = (blockIdx.x >> 6) * 32;
    const int tid = threadIdx.x;
    const int wv  = tid >> 6, lane = tid & 63;
    const int m   = lane & 15;
    const int kq  = (lane >> 4) * 8;
    const int rq  = (lane >> 4) * 4;

    // stage v[:, h0:h0+32] fp32 (coalesced)
    const float* vb = v + (size_t)b * SEQ * HID + h0;
    for (int f = tid; f < SEQ * 8; f += 512) {
        int r = f >> 3, c = (f & 7) << 2;
        *(float4*)&vraw[r][c] = *(const float4*)(vb + (size_t)r * HID + c);
    }
    __syncthreads();
    // transpose + split to bf16 hi/lo planes [h_local][j<=143]
    for (int it2 = tid; it2 < 32 * 36; it2 += 512) {
        int h = it2 & 31, j = (it2 >> 5) << 2;
        short4 hv, lv;
        split_bf16(j + 0 < SEQ ? vraw[j + 0][h] : 0.f, hv.x, lv.x);
        split_bf16(j + 1 < SEQ ? vraw[j + 1][h] : 0.f, hv.y, lv.y);
        split_bf16(j + 2 < SEQ ? vraw[j + 2][h] : 0.f, hv.z, lv.z);
        split_bf16(j + 3 < SEQ ? vraw[j + 3][h] : 0.f, hv.w, lv.w);
        *(short4*)&vth[h][j] = hv;
        *(short4*)&vtl[h][j] = lv;
    }
    __syncthreads();

    if (wv < 7) {
        const int i0 = wv * 16;
        int ai = i0 + m; if (ai > NKQ) ai = NKQ;      // clamp; C-rows >=101 unused
        const int ci = ai / KCLS;
        const float* ar = apad + ((size_t)b * SEQ + ai) * 128 + kq;
        f32x4 T[2] = {}, U[2] = {};
        #pragma unroll
        for (int ks = 0; ks < 4; ++ks) {
            float4 u0 = *(const float4*)(ar + ks * 32);
            float4 u1 = *(const float4*)(ar + ks * 32 + 4);
            float x[8] = {u0.x,u0.y,u0.z,u0.w,u1.x,u1.y,u1.z,u1.w};
            bf16x8 Ah, Al, Mh;
            #pragma unroll
            for (int e = 0; e < 8; ++e) {
                short h, l; split_bf16(x[e], h, l);
                Ah[e] = h; Al[e] = l;
                const int j = ks * 32 + kq + e;
                Mh[e] = ((j / KCLS) == ci) ? h : (short)0;
            }
            #pragma unroll
            for (int ht = 0; ht < 2; ++ht) {
                const bf16x8 Bh = *(const bf16x8*)&vth[ht * 16 + m][ks * 32 + kq];
                const bf16x8 Bl = *(const bf16x8*)&vtl[ht * 16 + m][ks * 32 + kq];
                T[ht] = __builtin_amdgcn_mfma_f32_16x16x32_bf16(Ah, Bh, T[ht], 0, 0, 0);
                T[ht] = __builtin_amdgcn_mfma_f32_16x16x32_bf16(Ah, Bl, T[ht], 0, 0, 0);
                T[ht] = __builtin_amdgcn_mfma_f32_16x16x32_bf16(Al, Bh, T[ht], 0, 0, 0);
                U[ht] = __builtin_amdgcn_mfma_f32_16x16x32_bf16(Mh, Bh, U[ht], 0, 0, 0);
            }
        }
        // epilogue: region-decomposed combine
        const float* ap = apad + (size_t)b * SEQ * 128;
        #pragma unroll
        for (int ht = 0; ht < 2; ++ht) {
            const int hl = ht * 16 + m;
            const int h  = h0 + hl;
            const float w0 = aw[0 * HID + h], w1 = aw[1 * HID + h], w2 = aw[2 * HID + h];
            const float w3 = aw[3 * HID + h], w4 = aw[4 * HID + h], w5 = aw[5 * HID + h];
            const float vN = vraw[NKQ][hl];
            #pragma unroll
            for (int r = 0; r < 4; ++r) {
                const int i = i0 + rq + r;
                if (i >= SEQ) continue;
                const float t = T[ht][r], u = U[ht][r];
                const float aiN = ap[(size_t)i * 128 + NKQ];
                float o;
                if (i < NKQ) {
                    const float aii = ap[(size_t)i * 128 + i];
                    const float vi  = vraw[i][hl];
                    o = w2 * t + (w1 - w2) * u + (w0 - w1) * aii * vi + (w3 - w2) * aiN * vN;
                } else {
                    o = w4 * t + (w5 - w4) * aiN * vN;
                }
                out[((size_t)b * SEQ + i) * HID + h] = o;
            }
        }
    }
}

extern "C" void kernel_launch(void* const* d_in, const int* in_sizes, int n_in,
                              void* d_out, int out_size, void* d_ws, size_t ws_size,
                              hipStream_t stream) {
    const float* q  = (const float*)d_in[0];
    const float* k  = (const float*)d_in[1];
    const float* v  = (const float*)d_in[2];
    const float* aw = (const float*)d_in[3];
    float* out  = (float*)d_out;
    float* attn = out + (size_t)BATCH * SEQ * HID;   // tuple output: [out | attn]
    float* apad = (float*)d_ws;                      // 64*101*128*4 = 3.3 MB

    qk_softmax<<<dim3(448), dim3(512), 0, stream>>>(q, k, attn, apad);
    pv_out<<<dim3(1024), dim3(512), 0, stream>>>(v, aw, apad, out);
}

// Round 9
// 119.403 us; speedup vs baseline: 1.5509x; 1.0593x over previous
//
#include <hip/hip_runtime.h>
#include <math.h>
#include <stdint.h>

#define BATCH 64
#define SEQ   101
#define HID   512
#define NKQ   100      // N*K
#define KCLS  10
#define INV_TEMP 0.04419417382415922f   // 1/sqrt(512)

typedef short bf16x8 __attribute__((ext_vector_type(8)));
typedef float f32x4  __attribute__((ext_vector_type(4)));

// truncation split: x == hi + lo to ~2^-17 rel
__device__ inline void split_bf16(float x, short& hi, short& lo) {
    uint32_t u = __builtin_bit_cast(uint32_t, x);
    hi = (short)(u >> 16);
    float hf = __builtin_bit_cast(float, u & 0xFFFF0000u);
    float l  = x - hf;
    lo = (short)(__builtin_bit_cast(uint32_t, l) >> 16);
}
// round-to-nearest-even bf16 (single-plane operands)
__device__ inline short rtn_bf16(float x) {
    uint32_t u = __builtin_bit_cast(uint32_t, x);
    return (short)((u + 0x7FFFu + ((u >> 16) & 1u)) >> 16);
}

// ---------------- K1: QK^T (LDS-staged bf16) + softmax ----------------------
// grid 448 flat: b = id&63 (XCD affinity), i-tile = id>>6. 512 thr = 8 waves.
// Per 64-wide k-chunk: block cooperatively stages k (128 j-rows, single bf16,
// RTN) and q (16 rows, hi/lo) into LDS; MFMA loop is pure ds_read_b128->MFMA.
// Wave w computes j-strip [16w,16w+16).
#define KCH 64
#define KST 72    // LDS row stride in shorts (144 B: 16B-aligned, bank-staggered)

__global__ __launch_bounds__(512, 4)
void qk_softmax(const float* __restrict__ q, const float* __restrict__ k,
                float* __restrict__ attn, float* __restrict__ apad) {
    __shared__ short khi[128][KST];   // 18.4 KB
    __shared__ short qhi[16][KST];    // 2.3 KB
    __shared__ short qlo[16][KST];    // 2.3 KB
    __shared__ float sc[16][132];     // 8.4 KB
    const int b   = blockIdx.x & 63;
    const int i0  = (blockIdx.x >> 6) * 16;
    const int tid = threadIdx.x;
    const int wv  = tid >> 6, lane = tid & 63;
    const int m   = lane & 15;
    const int kq  = (lane >> 4) * 8;
    const int rq  = (lane >> 4) * 4;
    const int j0w = wv * 16;

    const float* qb = q + (size_t)b * SEQ * HID;
    const float* kb = k + (size_t)b * SEQ * HID;

    f32x4 acc = {};
    for (int kc = 0; kc < HID; kc += KCH) {
        // stage k chunk: 128 rows x 64 floats = 2048 float4, 4 per thread
        #pragma unroll
        for (int s = 0; s < 4; ++s) {
            const int f = tid + s * 512;
            const int r = f >> 4, c = (f & 15) << 2;
            float4 x = make_float4(0.f, 0.f, 0.f, 0.f);
            if (r < SEQ) x = *(const float4*)(kb + (size_t)r * HID + kc + c);
            short4 hv;
            hv.x = rtn_bf16(x.x); hv.y = rtn_bf16(x.y);
            hv.z = rtn_bf16(x.z); hv.w = rtn_bf16(x.w);
            *(short4*)&khi[r][c] = hv;
        }
        // stage q chunk: 16 rows x 64 floats = 256 float4, threads [0,256)
        if (tid < 256) {
            const int r = tid >> 4, c = (tid & 15) << 2;
            const int gi = i0 + r;
            float4 x = make_float4(0.f, 0.f, 0.f, 0.f);
            if (gi < SEQ) x = *(const float4*)(qb + (size_t)gi * HID + kc + c);
            short4 hv, lv;
            split_bf16(x.x, hv.x, lv.x);
            split_bf16(x.y, hv.y, lv.y);
            split_bf16(x.z, hv.z, lv.z);
            split_bf16(x.w, hv.w, lv.w);
            *(short4*)&qhi[r][c] = hv;
            *(short4*)&qlo[r][c] = lv;
        }
        __syncthreads();
        // pure LDS->MFMA: 2 k-steps per chunk, 2 MFMA per step
        #pragma unroll
        for (int ks = 0; ks < KCH; ks += 32) {
            const bf16x8 qH = *(const bf16x8*)&qhi[m][ks + kq];
            const bf16x8 qL = *(const bf16x8*)&qlo[m][ks + kq];
            const bf16x8 kH = *(const bf16x8*)&khi[j0w + m][ks + kq];
            acc = __builtin_amdgcn_mfma_f32_16x16x32_bf16(qH, kH, acc, 0, 0, 0);
            acc = __builtin_amdgcn_mfma_f32_16x16x32_bf16(qL, kH, acc, 0, 0, 0);
        }
        __syncthreads();
    }
    #pragma unroll
    for (int r = 0; r < 4; ++r)
        sc[rq + r][j0w + m] = acc[r];
    __syncthreads();

    // softmax (32 threads per row) + attn + apad writes
    {
        const int row = tid >> 5, t32 = tid & 31;
        const int gi  = i0 + row;
        float mx = -1e30f;
        for (int j = t32; j < SEQ; j += 32) {
            float s = sc[row][j] * INV_TEMP;
            sc[row][j] = s;
            mx = fmaxf(mx, s);
        }
        #pragma unroll
        for (int off = 1; off < 32; off <<= 1) mx = fmaxf(mx, __shfl_xor(mx, off));
        float sum = 0.f;
        for (int j = t32; j < SEQ; j += 32) {
            float e = __expf(sc[row][j] - mx);
            sc[row][j] = e;
            sum += e;
        }
        #pragma unroll
        for (int off = 1; off < 32; off <<= 1) sum += __shfl_xor(sum, off);
        const float inv = 1.f / sum;
        if (gi < SEQ) {
            float* arow = attn + ((size_t)b * SEQ + gi) * SEQ;
            float* prow = apad + ((size_t)b * SEQ + gi) * 128;
            for (int j = t32; j < SEQ; j += 32) {
                float a = sc[row][j] * inv;
                arow[j] = a;
                prow[j] = a;
            }
            for (int j = SEQ + t32; j < 128; j += 32) prow[j] = 0.f;
        }
    }
}

// ---------------- K2: T = attn@v (hi/lo), U = amask@v; epilogue -------------
// grid 1024 flat: b = id&63, h-strip = (id>>6)*32. 512 thr = 8 waves.
#define VR 36     // vraw row stride (floats)
#define VT 144    // vt row stride (shorts)

__global__ __launch_bounds__(512, 6)
void pv_out(const float* __restrict__ v, const float* __restrict__ aw,
            const float* __restrict__ apad, float* __restrict__ out) {
    __shared__ float vraw[SEQ][VR];    // 14.5 KB (fp32 v strip, exact vi/vN)
    __shared__ short vth[32][VT];      // 9.2 KB
    __shared__ short vtl[32][VT];      // 9.2 KB
    const int b   = blockIdx.x & 63;
    const int h0  = (blockIdx.x >> 6) * 32;
    const int tid = threadIdx.x;
    const int wv  = tid >> 6, lane = tid & 63;
    const int m   = lane & 15;
    const int kq  = (lane >> 4) * 8;
    const int rq  = (lane >> 4) * 4;

    const float* vb = v + (size_t)b * SEQ * HID + h0;
    for (int f = tid; f < SEQ * 8; f += 512) {
        int r = f >> 3, c = (f & 7) << 2;
        *(float4*)&vraw[r][c] = *(const float4*)(vb + (size_t)r * HID + c);
    }
    __syncthreads();
    for (int it2 = tid; it2 < 32 * 36; it2 += 512) {
        int h = it2 & 31, j = (it2 >> 5) << 2;
        short4 hv, lv;
        split_bf16(j + 0 < SEQ ? vraw[j + 0][h] : 0.f, hv.x, lv.x);
        split_bf16(j + 1 < SEQ ? vraw[j + 1][h] : 0.f, hv.y, lv.y);
        split_bf16(j + 2 < SEQ ? vraw[j + 2][h] : 0.f, hv.z, lv.z);
        split_bf16(j + 3 < SEQ ? vraw[j + 3][h] : 0.f, hv.w, lv.w);
        *(short4*)&vth[h][j] = hv;
        *(short4*)&vtl[h][j] = lv;
    }
    __syncthreads();

    if (wv < 7) {
        const int i0 = wv * 16;
        int ai = i0 + m; if (ai > NKQ) ai = NKQ;      // clamp; C-rows >=101 unused
        const int ci = ai / KCLS;
        const float* ar = apad + ((size_t)b * SEQ + ai) * 128 + kq;
        f32x4 T[2] = {}, U[2] = {};
        #pragma unroll
        for (int ks = 0; ks < 4; ++ks) {
            float4 u0 = *(const float4*)(ar + ks * 32);
            float4 u1 = *(const float4*)(ar + ks * 32 + 4);
            float x[8] = {u0.x,u0.y,u0.z,u0.w,u1.x,u1.y,u1.z,u1.w};
            bf16x8 Ah, Al, Mh;
            #pragma unroll
            for (int e = 0; e < 8; ++e) {
                short h, l; split_bf16(x[e], h, l);
                Ah[e] = h; Al[e] = l;
                const int j = ks * 32 + kq + e;
                Mh[e] = ((j / KCLS) == ci) ? h : (short)0;
            }
            #pragma unroll
            for (int ht = 0; ht < 2; ++ht) {
                const bf16x8 Bh = *(const bf16x8*)&vth[ht * 16 + m][ks * 32 + kq];
                const bf16x8 Bl = *(const bf16x8*)&vtl[ht * 16 + m][ks * 32 + kq];
                T[ht] = __builtin_amdgcn_mfma_f32_16x16x32_bf16(Ah, Bh, T[ht], 0, 0, 0);
                T[ht] = __builtin_amdgcn_mfma_f32_16x16x32_bf16(Ah, Bl, T[ht], 0, 0, 0);
                T[ht] = __builtin_amdgcn_mfma_f32_16x16x32_bf16(Al, Bh, T[ht], 0, 0, 0);
                U[ht] = __builtin_amdgcn_mfma_f32_16x16x32_bf16(Mh, Bh, U[ht], 0, 0, 0);
            }
        }
        const float* ap = apad + (size_t)b * SEQ * 128;
        #pragma unroll
        for (int ht = 0; ht < 2; ++ht) {
            const int hl = ht * 16 + m;
            const int h  = h0 + hl;
            const float w0 = aw[0 * HID + h], w1 = aw[1 * HID + h], w2 = aw[2 * HID + h];
            const float w3 = aw[3 * HID + h], w4 = aw[4 * HID + h], w5 = aw[5 * HID + h];
            const float vN = vraw[NKQ][hl];
            #pragma unroll
            for (int r = 0; r < 4; ++r) {
                const int i = i0 + rq + r;
                if (i >= SEQ) continue;
                const float t = T[ht][r], u = U[ht][r];
                const float aiN = ap[(size_t)i * 128 + NKQ];
                float o;
                if (i < NKQ) {
                    const float aii = ap[(size_t)i * 128 + i];
                    const float vi  = vraw[i][hl];
                    o = w2 * t + (w1 - w2) * u + (w0 - w1) * aii * vi + (w3 - w2) * aiN * vN;
                } else {
                    o = w4 * t + (w5 - w4) * aiN * vN;
                }
                out[((size_t)b * SEQ + i) * HID + h] = o;
            }
        }
    }
}

extern "C" void kernel_launch(void* const* d_in, const int* in_sizes, int n_in,
                              void* d_out, int out_size, void* d_ws, size_t ws_size,
                              hipStream_t stream) {
    const float* q  = (const float*)d_in[0];
    const float* k  = (const float*)d_in[1];
    const float* v  = (const float*)d_in[2];
    const float* aw = (const float*)d_in[3];
    float* out  = (float*)d_out;
    float* attn = out + (size_t)BATCH * SEQ * HID;   // tuple output: [out | attn]
    float* apad = (float*)d_ws;                      // 64*101*128*4 = 3.3 MB

    qk_softmax<<<dim3(448), dim3(512), 0, stream>>>(q, k, attn, apad);
    pv_out<<<dim3(1024), dim3(512), 0, stream>>>(v, aw, apad, out);
}